// Round 9
// baseline (339.085 us; speedup 1.0000x reference)
//
#include <hip/hip_runtime.h>
#include <hip/hip_bf16.h>

typedef __bf16 bf16x8 __attribute__((ext_vector_type(8)));
typedef float f32x4 __attribute__((ext_vector_type(4)));
typedef unsigned int u32x4 __attribute__((ext_vector_type(4)));

#define MTOT    8192
#define DMODEL  768
#define DINNER  1536
#define DSTATE  128
#define NHEADS  24
#define CONVDIM 1792
#define LDZ     3328
#define SEQ     2048
#define CHUNK   128
#define NCHUNK  16
#define NBH     96

#define NU   (MTOT*DMODEL)
#define NWI  (LDZ*DMODEL)
#define NWO  (DMODEL*DINNER)
#define NWD  (32*DMODEL)

// async global->LDS, 16B per lane; LDS dest = wave-uniform base + lane*16
__device__ __forceinline__ void gl2lds16(const __hip_bfloat16* g, __hip_bfloat16* l) {
  __builtin_amdgcn_global_load_lds((const __attribute__((address_space(1))) void*)g,
                                   (__attribute__((address_space(3))) void*)l, 16, 0, 0);
}

// ---------------- f32 -> bf16 conversions (+ padded hi/lo dt weights) ----------------
__global__ __launch_bounds__(256) void cvt_bf16(const float* __restrict__ u, const float* __restrict__ Wi,
                                                const float* __restrict__ Wo,
                                                __hip_bfloat16* __restrict__ ub, __hip_bfloat16* __restrict__ wib,
                                                __hip_bfloat16* __restrict__ wob,
                                                __hip_bfloat16* __restrict__ wdh, __hip_bfloat16* __restrict__ wdl) {
  int i = blockIdx.x * 256 + threadIdx.x;
  if (i < NU) ub[i] = __float2bfloat16(u[i]);
  else if (i < NU + NWI) { int k = i - NU; wib[k] = __float2bfloat16(Wi[k]); }
  else if (i < NU + NWI + NWO) { int k = i - NU - NWI; wob[k] = __float2bfloat16(Wo[k]); }
  else if (i < NU + NWI + NWO + 2 * NWD) {
    int k = i - NU - NWI - NWO;
    int lo = (k >= NWD);
    if (lo) k -= NWD;
    int row = k / DMODEL, col = k - row * DMODEL;
    float w = (row < NHEADS) ? Wi[(size_t)(LDZ + row) * DMODEL + col] : 0.f;
    __hip_bfloat16 h = __float2bfloat16(w);
    if (!lo) wdh[k] = h;
    else wdl[k] = __float2bfloat16(w - __bfloat162float(h));
  }
}

// ============ ring-4 K=32-sub bf16 NT GEMM (T1+T2+T3+T4+T5, counted vmcnt) ============
// C[m][n] = sum_k A[m][k]*B[n][k]. Phase per K=32 sub: stage sub t+3, ds_read sub t,
// FM*FN MFMAs, vmcnt(8) [2 subs in flight], 1 barrier. Slot reuse distance 3 phases.
// LDS swizzle: phys 16B-chunk = logical ^ ((row>>1)&3); staging source pre-applies it.
#define STG_R(s)                                                                               \
  {                                                                                            \
    const int sl_ = (s) & 3;                                                                   \
    _Pragma("unroll") for (int i_ = 0; i_ < CA; ++i_)                                          \
        gl2lds16(Ag + (size_t)(i_ * RA) * lda + (s) * 32, &As[sl_][i_ * (T * 8) + tid * 8]);   \
    _Pragma("unroll") for (int i_ = 0; i_ < CB; ++i_)                                          \
        gl2lds16(Bg + (size_t)(i_ * RA) * ldb + (s) * 32, &Bs[sl_][i_ * (T * 8) + tid * 8]);   \
  }

#define PHASE_R(t, DOSTG, VMW)                                                                 \
  {                                                                                            \
    if (DOSTG) STG_R((t) + 3);                                                                 \
    const int sl_ = (t) & 3;                                                                   \
    bf16x8 fa_[FM], fb_[FN];                                                                   \
    _Pragma("unroll") for (int i_ = 0; i_ < FM; ++i_)                                          \
        fa_[i_] = *(const bf16x8*)&As[sl_][(wm * PM + i_ * 16 + lr) * 32 + rch];               \
    _Pragma("unroll") for (int j_ = 0; j_ < FN; ++j_)                                          \
        fb_[j_] = *(const bf16x8*)&Bs[sl_][(wn * PN + j_ * 16 + lr) * 32 + rch];               \
    __builtin_amdgcn_s_setprio(1);                                                             \
    _Pragma("unroll") for (int i_ = 0; i_ < FM; ++i_)                                          \
        _Pragma("unroll") for (int j_ = 0; j_ < FN; ++j_)                                      \
            acc[i_][j_] =                                                                      \
                __builtin_amdgcn_mfma_f32_16x16x32_bf16(fa_[i_], fb_[j_], acc[i_][j_], 0, 0, 0); \
    __builtin_amdgcn_s_setprio(0);                                                             \
    VMW;                                                                                       \
    __builtin_amdgcn_sched_barrier(0);                                                         \
    __builtin_amdgcn_s_barrier();                                                              \
    __builtin_amdgcn_sched_barrier(0);                                                         \
  }

template <int BM, int BN, int WGM, int WGN, typename OutT>
__global__ __launch_bounds__(WGM * WGN * 64, 2) void gemm_ring(const __hip_bfloat16* __restrict__ A,
                                                               const __hip_bfloat16* __restrict__ B,
                                                               OutT* __restrict__ C, int lda, int ldb,
                                                               int ldc, int nsub, int nbn) {
  constexpr int T = WGM * WGN * 64;
  constexpr int PM = BM / WGM, PN = BN / WGN;
  constexpr int FM = PM / 16, FN = PN / 16;
  constexpr int CA = (BM * 64) / (T * 16);  // gl2lds calls per A sub
  constexpr int CB = (BN * 64) / (T * 16);
  constexpr int RA = T / 4;                 // rows covered per call
  __shared__ __align__(16) __hip_bfloat16 As[4][BM * 32];
  __shared__ __align__(16) __hip_bfloat16 Bs[4][BN * 32];
  const int tid = threadIdx.x;
  const int lane = tid & 63, wid = tid >> 6;
  const int wm = wid / WGN, wn = wid % WGN;
  const int lr = lane & 15, lk = lane >> 4;
  // T1 bijective XCD swizzle (grid % 8 == 0)
  const int cpx = (int)gridDim.x >> 3;
  const int swz = ((int)blockIdx.x & 7) * cpx + ((int)blockIdx.x >> 3);
  const int bn = swz % nbn, bm = swz / nbn;
  // staging source (pre-swizzled): thread t -> row t>>2, phys chunk t&3 holds logical (t&3)^((t>>3)&3)
  const int srow = tid >> 2;
  const int scol = ((tid & 3) ^ ((tid >> 3) & 3)) * 8;
  const __hip_bfloat16* Ag = A + (size_t)(bm * BM + srow) * lda + scol;
  const __hip_bfloat16* Bg = B + (size_t)(bn * BN + srow) * ldb + scol;
  const int rch = (lk ^ ((lr >> 1) & 3)) * 8;  // read-side swizzled chunk
  f32x4 acc[FM][FN] = {};

  STG_R(0); STG_R(1); STG_R(2);
  asm volatile("s_waitcnt vmcnt(8)" ::: "memory");
  __builtin_amdgcn_sched_barrier(0);
  __builtin_amdgcn_s_barrier();
  __builtin_amdgcn_sched_barrier(0);
  int t = 0;
  for (; t < nsub - 3; ++t) PHASE_R(t, true, asm volatile("s_waitcnt vmcnt(8)" ::: "memory"));
  PHASE_R(t, false, asm volatile("s_waitcnt vmcnt(4)" ::: "memory")); ++t;
  PHASE_R(t, false, asm volatile("s_waitcnt vmcnt(0)" ::: "memory")); ++t;
  PHASE_R(t, false, (void)0);

  const int crow0 = bm * BM + wm * PM + lk * 4;
  const int ccol0 = bn * BN + wn * PN + lr;
#pragma unroll
  for (int mf = 0; mf < FM; ++mf)
#pragma unroll
    for (int nf = 0; nf < FN; ++nf)
#pragma unroll
      for (int r = 0; r < 4; ++r)
        C[(size_t)(crow0 + mf * 16 + r) * ldc + ccol0 + nf * 16] = (OutT)acc[mf][nf][r];
}

// ---------------- dt path: split-bf16 MFMA GEMM (fp32-grade) + softplus epilogue ----------------
__global__ __launch_bounds__(256) void dt_mfma(const float* __restrict__ u,
                                               const __hip_bfloat16* __restrict__ wdh,
                                               const __hip_bfloat16* __restrict__ wdl,
                                               const float* __restrict__ dtb, const float* __restrict__ alog,
                                               float* __restrict__ dtS, float* __restrict__ dtA) {
  __shared__ __align__(16) __hip_bfloat16 Uh[64 * 32];
  __shared__ __align__(16) __hip_bfloat16 Ul[64 * 32];
  const int tid = threadIdx.x;
  const int lane = tid & 63, wid = tid >> 6;
  const int lr = lane & 15, lk = lane >> 4;
  const int bm = blockIdx.x;
  const int r = tid >> 2, c0 = (tid & 3) * 8;
  const float* usrc = u + (size_t)(bm * 64 + r) * DMODEL + c0;
  f32x4 acc[2] = {};
  for (int ks = 0; ks < DMODEL / 32; ++ks) {
    float4 v0 = *(const float4*)(usrc + ks * 32);
    float4 v1 = *(const float4*)(usrc + ks * 32 + 4);
    bf16x8 hi, lo;
    const float* vf = (const float*)&v0;
#pragma unroll
    for (int e = 0; e < 4; ++e) {
      __hip_bfloat16 h = __float2bfloat16(vf[e]);
      hi[e] = *(__bf16*)&h;
      __hip_bfloat16 l2 = __float2bfloat16(vf[e] - __bfloat162float(h));
      lo[e] = *(__bf16*)&l2;
    }
    vf = (const float*)&v1;
#pragma unroll
    for (int e = 0; e < 4; ++e) {
      __hip_bfloat16 h = __float2bfloat16(vf[e]);
      hi[4 + e] = *(__bf16*)&h;
      __hip_bfloat16 l2 = __float2bfloat16(vf[e] - __bfloat162float(h));
      lo[4 + e] = *(__bf16*)&l2;
    }
    *(bf16x8*)&Uh[r * 32 + c0] = hi;
    *(bf16x8*)&Ul[r * 32 + c0] = lo;
    __syncthreads();
    bf16x8 ah = *(const bf16x8*)&Uh[(wid * 16 + lr) * 32 + lk * 8];
    bf16x8 al = *(const bf16x8*)&Ul[(wid * 16 + lr) * 32 + lk * 8];
#pragma unroll
    for (int j = 0; j < 2; ++j) {
      bf16x8 bh = *(const bf16x8*)(wdh + (size_t)(j * 16 + lr) * DMODEL + ks * 32 + lk * 8);
      bf16x8 bl = *(const bf16x8*)(wdl + (size_t)(j * 16 + lr) * DMODEL + ks * 32 + lk * 8);
      acc[j] = __builtin_amdgcn_mfma_f32_16x16x32_bf16(ah, bh, acc[j], 0, 0, 0);
      acc[j] = __builtin_amdgcn_mfma_f32_16x16x32_bf16(ah, bl, acc[j], 0, 0, 0);
      acc[j] = __builtin_amdgcn_mfma_f32_16x16x32_bf16(al, bh, acc[j], 0, 0, 0);
    }
    __syncthreads();
  }
#pragma unroll
  for (int j = 0; j < 2; ++j) {
    int col = j * 16 + lr;
    if (col < NHEADS) {
      float nA = -expf(alog[col]);
      float bia = dtb[col];
#pragma unroll
      for (int rr = 0; rr < 4; ++rr) {
        int row = bm * 64 + wid * 16 + lk * 4 + rr;
        float x = acc[j][rr] + bia;
        float dt = (x > 20.f) ? x : log1pf(expf(x));
        dtS[(size_t)row * NHEADS + col] = dt;
        dtA[(size_t)row * NHEADS + col] = nA * dt;
      }
    }
  }
}

// ---------------- per-(b,chunk) cumsum of dt*A over time ----------------
__global__ __launch_bounds__(256) void cumsum_kernel(const float* __restrict__ dtA, float* __restrict__ scum,
                                                     float* __restrict__ cdec) {
  int bc = blockIdx.x;
  int b = bc >> 4, c = bc & 15;
  __shared__ float buf[CHUNK * NHEADS];
  int m0 = b * SEQ + c * CHUNK;
  for (int t = threadIdx.x; t < CHUNK * NHEADS; t += 256)
    buf[t] = dtA[(size_t)m0 * NHEADS + t];
  __syncthreads();
  if (threadIdx.x < NHEADS) {
    int h = threadIdx.x;
    float run = 0.f;
    float* dst = scum + ((size_t)bc * NHEADS + h) * CHUNK;
    for (int j = 0; j < CHUNK; ++j) { run += buf[j * NHEADS + h]; dst[j] = run; }
    cdec[(b * NHEADS + h) * NCHUNK + c] = __expf(run);
  }
}

// ---------------- fused conv + silu + bf16 pack + transpose (reads bf16 zxb) ----------------
__global__ __launch_bounds__(256) void conv_fused(const __hip_bfloat16* __restrict__ zxb,
                                                  const float* __restrict__ cw,
                                                  const float* __restrict__ cb, const float* __restrict__ dtS,
                                                  __hip_bfloat16* __restrict__ Xd, __hip_bfloat16* __restrict__ Bb,
                                                  __hip_bfloat16* __restrict__ Cb, __hip_bfloat16* __restrict__ XdT,
                                                  __hip_bfloat16* __restrict__ Bt) {
  __shared__ __hip_bfloat16 t[64][72];
  __shared__ float dts_sh[64];
  const int c0 = blockIdx.x * 64, m0 = blockIdx.y * 64;
  const int b = m0 >> 11, l0 = m0 & (SEQ - 1);
  const int tid = threadIdx.x;
  const int c = tid & 63, rg = tid >> 6;
  const int gc = c0 + c;
  const bool isX = (c0 < DINNER);
  if (isX && tid < 64) dts_sh[tid] = dtS[(size_t)(m0 + tid) * NHEADS + (c0 >> 6)];
  const float4 w = *(const float4*)(cw + (size_t)gc * 4);
  const float bias = cb[gc];
  const __hip_bfloat16* src = zxb + (size_t)(m0 + rg * 16) * LDZ + DINNER + gc;
  const int lbase = l0 + rg * 16;
  float v0 = (lbase >= 3) ? __bfloat162float(src[-3 * (ptrdiff_t)LDZ]) : 0.f;
  float v1 = (lbase >= 2) ? __bfloat162float(src[-2 * (ptrdiff_t)LDZ]) : 0.f;
  float v2 = (lbase >= 1) ? __bfloat162float(src[-1 * (ptrdiff_t)LDZ]) : 0.f;
  __syncthreads();
#pragma unroll
  for (int r = 0; r < 16; ++r) {
    float v3 = __bfloat162float(src[(ptrdiff_t)r * LDZ]);
    float a = bias + v0 * w.x + v1 * w.y + v2 * w.z + v3 * w.w;
    float sv = a / (1.f + __expf(-a));
    int lm = rg * 16 + r;
    __hip_bfloat16 val = __float2bfloat16(isX ? dts_sh[lm] * sv : sv);
    t[lm][c] = val;
    int m = m0 + lm;
    if (isX) Xd[(size_t)m * DINNER + gc] = val;
    else if (gc < DINNER + DSTATE) Bb[(size_t)m * DSTATE + gc - DINNER] = val;
    else Cb[(size_t)m * DSTATE + gc - DINNER - DSTATE] = val;
    v0 = v1; v1 = v2; v2 = v3;
  }
  __syncthreads();
  if (c0 < DINNER + DSTATE) {
    int r2 = tid >> 2, cc = (tid & 3) * 16;
    __hip_bfloat16 tmp[16] __attribute__((aligned(16)));
#pragma unroll
    for (int k = 0; k < 16; ++k) tmp[k] = t[cc + k][r2];
    __hip_bfloat16* dst = isX ? XdT + ((size_t)(b * DINNER + c0 + r2)) * SEQ + l0 + cc
                              : Bt + ((size_t)(b * DSTATE + (c0 - DINNER) + r2)) * SEQ + l0 + cc;
    *(u32x4*)dst = *(u32x4*)&tmp[0];
    *(u32x4*)(dst + 8) = *(u32x4*)&tmp[8];
  }
}

// ---------------- chunk-local end state -> bf16 ----------------
__global__ __launch_bounds__(256, 2) void state_gemm(const __hip_bfloat16* __restrict__ XdT,
                                                     const __hip_bfloat16* __restrict__ Bt,
                                                     const float* __restrict__ scum,
                                                     __hip_bfloat16* __restrict__ cstat) {
  __shared__ __align__(16) __hip_bfloat16 Xw[64 * 136];
  __shared__ __align__(16) __hip_bfloat16 Bts[128 * 136];
  __shared__ float rS[CHUNK];
  int bid = blockIdx.x;
  int c = bid & 15, bh = bid >> 4;
  int b = bh / NHEADS, h = bh % NHEADS;
  const float* sp = scum + ((size_t)(b * NCHUNK + c) * NHEADS + h) * CHUNK;
  int tid = threadIdx.x;
  if (tid < CHUNK) rS[tid] = __expf(sp[CHUNK - 1] - sp[tid]);
  {
    int n = tid >> 1, jc = (tid & 1) * 64;
    const __hip_bfloat16* g = Bt + ((size_t)(b * DSTATE + n)) * SEQ + c * CHUNK + jc;
#pragma unroll
    for (int q = 0; q < 8; ++q) *(u32x4*)&Bts[n * 136 + jc + q * 8] = *(const u32x4*)(g + q * 8);
  }
  __syncthreads();
  {
    int p = tid >> 2, jc = (tid & 3) * 32;
    const __hip_bfloat16* g = XdT + ((size_t)((b * NHEADS + h) * 64 + p)) * SEQ + c * CHUNK + jc;
#pragma unroll
    for (int q = 0; q < 4; ++q) {
      bf16x8 vv = *(const bf16x8*)(g + q * 8);
      bf16x8 ov;
#pragma unroll
      for (int e = 0; e < 8; ++e) ov[e] = (__bf16)((float)vv[e] * rS[jc + q * 8 + e]);
      *(bf16x8*)&Xw[p * 136 + jc + q * 8] = ov;
    }
  }
  __syncthreads();
  const int lane = tid & 63, wid = tid >> 6;
  const int wm = wid >> 1, wn = wid & 1;
  const int lr = lane & 15, lk = lane >> 4;
  f32x4 acc[2][4] = {};
#pragma unroll
  for (int ks = 0; ks < 4; ++ks) {
    bf16x8 af[2], bq[4];
#pragma unroll
    for (int i = 0; i < 2; ++i) af[i] = *(const bf16x8*)&Xw[(wm * 32 + i * 16 + lr) * 136 + ks * 32 + lk * 8];
#pragma unroll
    for (int j = 0; j < 4; ++j) bq[j] = *(const bf16x8*)&Bts[(wn * 64 + j * 16 + lr) * 136 + ks * 32 + lk * 8];
#pragma unroll
    for (int i = 0; i < 2; ++i)
#pragma unroll
      for (int j = 0; j < 4; ++j)
        acc[i][j] = __builtin_amdgcn_mfma_f32_16x16x32_bf16(af[i], bq[j], acc[i][j], 0, 0, 0);
  }
  __hip_bfloat16* dst = cstat + (size_t)bid * 8192;
#pragma unroll
  for (int i = 0; i < 2; ++i)
#pragma unroll
    for (int j = 0; j < 4; ++j)
#pragma unroll
      for (int r = 0; r < 4; ++r)
        dst[(wm * 32 + i * 16 + lk * 4 + r) * 128 + wn * 64 + j * 16 + lr] = __float2bfloat16(acc[i][j][r]);
}

// ---------------- inter-chunk recurrence (bf16 states, f32 accum) ----------------
__global__ __launch_bounds__(256) void scanB(__hip_bfloat16* __restrict__ cstat, const float* __restrict__ cdec) {
  const int bh = blockIdx.x >> 3, sl = blockIdx.x & 7;
  const int base = sl * 1024 + threadIdx.x * 4;
  float hreg[4] = {0.f, 0.f, 0.f, 0.f};
  for (int c = 0; c < NCHUNK; ++c) {
    __hip_bfloat16* p = cstat + (size_t)(bh * NCHUNK + c) * 8192 + base;
    const float P = cdec[bh * NCHUNK + c];
    __hip_bfloat16 tmp[4], hs[4];
    *(uint2*)tmp = *(const uint2*)p;
#pragma unroll
    for (int j = 0; j < 4; ++j) hs[j] = __float2bfloat16(hreg[j]);
    *(uint2*)p = *(uint2*)hs;
#pragma unroll
    for (int j = 0; j < 4; ++j) hreg[j] = fmaf(hreg[j], P, __bfloat162float(tmp[j]));
  }
}

// ---------------- SSD y kernel (y out: bf16 into zxb) ----------------
template <int JE>
__global__ __launch_bounds__(256, 2) void ssd_y(const __hip_bfloat16* __restrict__ Cb,
                                                const __hip_bfloat16* __restrict__ Bb,
                                                const __hip_bfloat16* __restrict__ XdT,
                                                const __hip_bfloat16* __restrict__ Xd,
                                                const __hip_bfloat16* __restrict__ cstat,
                                                const float* __restrict__ scum,
                                                const float* __restrict__ dtS, const float* __restrict__ Dvec,
                                                __hip_bfloat16* __restrict__ zxb) {
  constexpr int HI = JE - 64;
  constexpr int JW = JE / 2;
  constexpr int FJ = JW / 16;
  constexpr int KJ = JE / 32;
  __shared__ __align__(16) __hip_bfloat16 Cs[64 * 136];
  __shared__ __align__(16) __hip_bfloat16 Bs[JE * 136];
  __shared__ __align__(16) __hip_bfloat16 R3[64 * 136];
  __shared__ float sS[CHUNK];
  int bid = blockIdx.x;
  int c = bid & 15, bh = bid >> 4;
  int b = bh / NHEADS, h = bh % NHEADS;
  int m0 = b * SEQ + c * CHUNK;
  int tid = threadIdx.x;
  const float* sp = scum + ((size_t)(b * NCHUNK + c) * NHEADS + h) * CHUNK;
  if (tid < CHUNK) sS[tid] = sp[tid];
  {
    int r = tid >> 2, nc = (tid & 3) * 32;
    const __hip_bfloat16* g = Cb + (size_t)(m0 + HI + r) * DSTATE + nc;
#pragma unroll
    for (int q = 0; q < 4; ++q) *(u32x4*)&Cs[r * 136 + nc + q * 8] = *(const u32x4*)(g + q * 8);
  }
  if (JE == 64) {
    int r = tid >> 2, nc = (tid & 3) * 32;
    const __hip_bfloat16* g = Bb + (size_t)(m0 + r) * DSTATE + nc;
#pragma unroll
    for (int q = 0; q < 4; ++q) *(u32x4*)&Bs[r * 136 + nc + q * 8] = *(const u32x4*)(g + q * 8);
  } else {
    int r = tid >> 1, nc = (tid & 1) * 64;
    const __hip_bfloat16* g = Bb + (size_t)(m0 + r) * DSTATE + nc;
#pragma unroll
    for (int q = 0; q < 8; ++q) *(u32x4*)&Bs[r * 136 + nc + q * 8] = *(const u32x4*)(g + q * 8);
  }
  {
    int p = tid >> 2, nc = (tid & 3) * 32;
    const __hip_bfloat16* g = cstat + (size_t)bid * 8192 + p * 128 + nc;
#pragma unroll
    for (int q = 0; q < 4; ++q) *(u32x4*)&R3[p * 136 + nc + q * 8] = *(const u32x4*)(g + q * 8);
  }
  __syncthreads();
  const int lane = tid & 63, wid = tid >> 6;
  const int wm = wid >> 1, wn = wid & 1;
  const int lr = lane & 15, lk = lane >> 4;
  f32x4 Gacc[2][FJ] = {};
  f32x4 Uacc[2][2] = {};
#pragma unroll
  for (int ks = 0; ks < 4; ++ks) {
    bf16x8 af[2], bq[2];
#pragma unroll
    for (int i = 0; i < 2; ++i) af[i] = *(const bf16x8*)&Cs[(wm * 32 + i * 16 + lr) * 136 + ks * 32 + lk * 8];
#pragma unroll
    for (int j = 0; j < 2; ++j) bq[j] = *(const bf16x8*)&R3[(wn * 32 + j * 16 + lr) * 136 + ks * 32 + lk * 8];
#pragma unroll
    for (int i = 0; i < 2; ++i)
#pragma unroll
      for (int j = 0; j < 2; ++j)
        Uacc[i][j] = __builtin_amdgcn_mfma_f32_16x16x32_bf16(af[i], bq[j], Uacc[i][j], 0, 0, 0);
  }
#pragma unroll
  for (int ks = 0; ks < 4; ++ks) {
    bf16x8 af[2], bq[FJ];
#pragma unroll
    for (int i = 0; i < 2; ++i) af[i] = *(const bf16x8*)&Cs[(wm * 32 + i * 16 + lr) * 136 + ks * 32 + lk * 8];
#pragma unroll
    for (int j = 0; j < FJ; ++j) bq[j] = *(const bf16x8*)&Bs[(wn * JW + j * 16 + lr) * 136 + ks * 32 + lk * 8];
#pragma unroll
    for (int i = 0; i < 2; ++i)
#pragma unroll
      for (int j = 0; j < FJ; ++j)
        Gacc[i][j] = __builtin_amdgcn_mfma_f32_16x16x32_bf16(af[i], bq[j], Gacc[i][j], 0, 0, 0);
  }
  __syncthreads();
  {
    float siv[2][4];
#pragma unroll
    for (int i = 0; i < 2; ++i)
#pragma unroll
      for (int r = 0; r < 4; ++r) siv[i][r] = sS[HI + wm * 32 + i * 16 + lk * 4 + r];
#pragma unroll
    for (int i = 0; i < 2; ++i)
#pragma unroll
      for (int j = 0; j < FJ; ++j) {
        int gj = wn * JW + j * 16 + lr;
        float sj = sS[gj];
#pragma unroll
        for (int r = 0; r < 4; ++r) {
          int il = wm * 32 + i * 16 + lk * 4 + r;
          int gi = HI + il;
          float mv = (gj <= gi) ? Gacc[i][j][r] * __expf(siv[i][r] - sj) : 0.f;
          Cs[il * 136 + gj] = __float2bfloat16(mv);
        }
      }
  }
  {
    int p = tid >> 2, jc = (tid & 3) * (JE / 4);
    const __hip_bfloat16* g = XdT + ((size_t)((b * NHEADS + h) * 64 + p)) * SEQ + c * CHUNK + jc;
#pragma unroll
    for (int q = 0; q < JE / 32; ++q) *(u32x4*)&R3[p * 136 + jc + q * 8] = *(const u32x4*)(g + q * 8);
  }
  __syncthreads();
  f32x4 Yacc[2][2] = {};
#pragma unroll
  for (int ks = 0; ks < KJ; ++ks) {
    bf16x8 af[2], bq[2];
#pragma unroll
    for (int i = 0; i < 2; ++i) af[i] = *(const bf16x8*)&Cs[(wm * 32 + i * 16 + lr) * 136 + ks * 32 + lk * 8];
#pragma unroll
    for (int j = 0; j < 2; ++j) bq[j] = *(const bf16x8*)&R3[(wn * 32 + j * 16 + lr) * 136 + ks * 32 + lk * 8];
#pragma unroll
    for (int i = 0; i < 2; ++i)
#pragma unroll
      for (int j = 0; j < 2; ++j)
        Yacc[i][j] = __builtin_amdgcn_mfma_f32_16x16x32_bf16(af[i], bq[j], Yacc[i][j], 0, 0, 0);
  }
  const float Dh = Dvec[h];
#pragma unroll
  for (int i = 0; i < 2; ++i)
#pragma unroll
    for (int r = 0; r < 4; ++r) {
      int il = wm * 32 + i * 16 + lk * 4 + r;
      int gi = HI + il;
      int m = m0 + gi;
      float ei = __expf(sS[gi]);
      float dt = dtS[(size_t)m * NHEADS + h];
#pragma unroll
      for (int j = 0; j < 2; ++j) {
        int p = wn * 32 + j * 16 + lr;
        float xv = (float)Xd[(size_t)m * DINNER + h * 64 + p] / dt;
        zxb[(size_t)m * LDZ + DINNER + h * 64 + p] =
            __float2bfloat16(Yacc[i][j][r] + ei * Uacc[i][j][r] + Dh * xv);
      }
    }
}

// ---------------- RMSNorm + silu(z) gate (bf16 in) -> bf16 ----------------
__global__ __launch_bounds__(192) void norm_gate(const __hip_bfloat16* __restrict__ zxb,
                                                 const float* __restrict__ nw,
                                                 __hip_bfloat16* __restrict__ yg) {
  const int m = blockIdx.x, tid = threadIdx.x;
  const __hip_bfloat16* zr = zxb + (size_t)m * LDZ;
  const __hip_bfloat16* yr = zr + DINNER;
  bf16x8 y8 = *(const bf16x8*)&yr[tid * 8];
  bf16x8 z8 = *(const bf16x8*)&zr[tid * 8];
  float yv[8], zv[8];
  float ss = 0.f;
#pragma unroll
  for (int e = 0; e < 8; ++e) {
    yv[e] = (float)y8[e];
    zv[e] = (float)z8[e];
    ss = fmaf(yv[e], yv[e], ss);
  }
#pragma unroll
  for (int o = 32; o > 0; o >>= 1) ss += __shfl_down(ss, o);
  __shared__ float red[3];
  if ((tid & 63) == 0) red[tid >> 6] = ss;
  __syncthreads();
  float tot = red[0] + red[1] + red[2];
  float r = rsqrtf(tot * (1.f / 1536.f) + 1e-5f);
  float4 w0 = *(const float4*)&nw[tid * 8];
  float4 w1 = *(const float4*)&nw[tid * 8 + 4];
  const float* wf = (const float*)&w0;
  bf16x8 o8;
#pragma unroll
  for (int e = 0; e < 8; ++e) {
    float wv = (e < 4) ? wf[e] : ((const float*)&w1)[e - 4];
    float g = zv[e] / (1.f + __expf(-zv[e]));
    o8[e] = (__bf16)(wv * yv[e] * r * g);
  }
  *(bf16x8*)&yg[(size_t)m * DINNER + tid * 8] = o8;
}

extern "C" void kernel_launch(void* const* d_in, const int* in_sizes, int n_in,
                              void* d_out, int out_size, void* d_ws, size_t ws_size,
                              hipStream_t stream) {
  (void)in_sizes; (void)n_in; (void)out_size; (void)ws_size;
  const float* u       = (const float*)d_in[0];
  const float* W_in    = (const float*)d_in[1];
  const float* conv_w  = (const float*)d_in[2];
  const float* conv_b  = (const float*)d_in[3];
  const float* dt_bias = (const float*)d_in[4];
  const float* A_log   = (const float*)d_in[5];
  const float* Dvec    = (const float*)d_in[6];
  const float* norm_w  = (const float*)d_in[7];
  const float* W_out   = (const float*)d_in[8];
  float* out = (float*)d_out;

  __hip_bfloat16* zxbb = (__hip_bfloat16*)d_ws;                       // [8192][3328] bf16
  __hip_bfloat16* cstatb = zxbb + (size_t)MTOT * LDZ;                 // [1536][8192] bf16
  float* dtS  = (float*)(cstatb + (size_t)NBH * NCHUNK * 8192);
  float* dtA  = dtS + (size_t)MTOT * NHEADS;
  float* scum = dtA + (size_t)MTOT * NHEADS;
  float* cdec = scum + (size_t)MTOT * NHEADS;
  __hip_bfloat16* ub  = (__hip_bfloat16*)(cdec + NBH * NCHUNK);
  __hip_bfloat16* wib = ub + (size_t)NU;
  __hip_bfloat16* wob = wib + (size_t)NWI;
  __hip_bfloat16* wdh = wob + (size_t)NWO;
  __hip_bfloat16* wdl = wdh + (size_t)NWD;
  __hip_bfloat16* Xd  = wdl + (size_t)NWD;
  __hip_bfloat16* Bb  = Xd + (size_t)MTOT * DINNER;
  __hip_bfloat16* Cb  = Bb + (size_t)MTOT * DSTATE;
  __hip_bfloat16* XdT = Cb + (size_t)MTOT * DSTATE;
  __hip_bfloat16* Bt  = XdT + (size_t)MTOT * DINNER;
  __hip_bfloat16* yg  = Xd;  // alias: Xd dead after ssd_y

  cvt_bf16<<<(NU + NWI + NWO + 2 * NWD + 255) / 256, 256, 0, stream>>>(u, W_in, W_out, ub, wib, wob, wdh, wdl);
  gemm_ring<256, 256, 2, 4, __hip_bfloat16><<<(LDZ / 256) * (MTOT / 256), 512, 0, stream>>>(
      ub, wib, zxbb, DMODEL, DMODEL, LDZ, DMODEL / 32, LDZ / 256);
  dt_mfma<<<MTOT / 64, 256, 0, stream>>>(u, wdh, wdl, dt_bias, A_log, dtS, dtA);
  cumsum_kernel<<<64, 256, 0, stream>>>(dtA, scum, cdec);
  conv_fused<<<dim3(CONVDIM / 64, MTOT / 64), 256, 0, stream>>>(zxbb, conv_w, conv_b, dtS, Xd, Bb, Cb, XdT, Bt);
  state_gemm<<<NBH * NCHUNK, 256, 0, stream>>>(XdT, Bt, scum, cstatb);
  scanB<<<NBH * 8, 256, 0, stream>>>(cstatb, cdec);
  ssd_y<64><<<NBH * NCHUNK, 256, 0, stream>>>(Cb, Bb, XdT, Xd, cstatb, scum, dtS, Dvec, zxbb);
  ssd_y<128><<<NBH * NCHUNK, 256, 0, stream>>>(Cb, Bb, XdT, Xd, cstatb, scum, dtS, Dvec, zxbb);
  norm_gate<<<MTOT, 192, 0, stream>>>(zxbb, norm_w, yg);
  gemm_ring<128, 128, 2, 2, float><<<(DMODEL / 128) * (MTOT / 128), 256, 0, stream>>>(
      yg, wob, out, DINNER, DINNER, DMODEL, DINNER / 32, DMODEL / 128);
}